// Round 6
// baseline (152.293 us; speedup 1.0000x reference)
//
#include <hip/hip_runtime.h>

#define IN_N   4096
#define OW     4084          // (4096 + 2*1 - 15) + 1
#define KS     15
#define TILE   64            // 64x64 output tile
#define XROWS  78            // TILE + 14 halo rows
#define XS     88            // LDS row stride in halfwords
#define TILES  4             // stacked row-tiles per block (pipeline depth)
#define NBX    64
#define NBY    16
#define NRT    64            // total row tiles

typedef __attribute__((ext_vector_type(8))) short     v8s;   // raw 16B
typedef __attribute__((ext_vector_type(8))) _Float16  v8h;   // f16 A/B frag (4 VGPR)
typedef __attribute__((ext_vector_type(4))) float     v4f;   // C/D frag
typedef __attribute__((ext_vector_type(2))) float     v2f;
typedef __attribute__((ext_vector_type(4))) unsigned  v4u;

// ---- pre-kernel: build the 15 banded-B MFMA fragments once into d_ws ----
// B_ky[k][n] = w[ky, k-1-n] (band k ∈ [n+1, n+15]); A k-window starts at EVEN
// global col X0-2 -> aligned float2 staging.
// lane e holds B[k = (e>>4)*8 + j][n = e&15], j = 0..7  (16 B per lane)
__global__ void build_B(const float* __restrict__ w, unsigned short* __restrict__ Bg) {
    int ky = blockIdx.x;         // 15
    int e  = threadIdx.x;        // 64
    int n = e & 15, quad = e >> 4;
    unsigned short vals[8];
    #pragma unroll
    for (int j = 0; j < 8; ++j) {
        int d = quad * 8 + j - 1 - n;                 // shifted band
        _Float16 h = (_Float16)0.0f;
        if (d >= 0 && d < KS) h = (_Float16)w[ky * KS + d];   // RTNE f32->f16
        union { _Float16 hh; unsigned short u; } cv; cv.hh = h;
        vals[j] = cv.u;
    }
    *(v8s*)(&Bg[(ky * 64 + e) * 8]) = *(const v8s*)vals;
}

__device__ __forceinline__ unsigned pk(float a, float b) {
    return __builtin_bit_cast(unsigned, __builtin_amdgcn_cvt_pkrtz(a, b));
}

// direct stage (prologue + edge tiles): load, cvt, write in one pass
__device__ __forceinline__ void stage_direct(
    const float* __restrict__ x, unsigned short* __restrict__ buf,
    int tid, int R0, int X0, bool fast)
{
    #pragma unroll
    for (int s = 0; s < 4; ++s) {
        int i = s * 256 + tid;
        if (i < XROWS * 10) {
            int row = i / 10, u = i - 10 * row;
            int gr  = R0 - 1 + row;
            int gc0 = X0 - 2 + 8 * u;
            v4u p;
            if (fast) {
                const float* xr = x + (size_t)gr * IN_N + gc0;
                v2f f0 = *(const v2f*)(xr + 0);
                v2f f1 = *(const v2f*)(xr + 2);
                v2f f2 = *(const v2f*)(xr + 4);
                v2f f3 = *(const v2f*)(xr + 6);
                p.x = pk(f0.x, f0.y); p.y = pk(f1.x, f1.y);
                p.z = pk(f2.x, f2.y); p.w = pk(f3.x, f3.y);
            } else {
                float f[8];
                #pragma unroll
                for (int j = 0; j < 8; ++j) f[j] = 0.0f;
                if ((unsigned)gr < (unsigned)IN_N) {
                    const float* xr = x + (size_t)gr * IN_N;
                    #pragma unroll
                    for (int j = 0; j < 8; ++j)
                        if ((unsigned)(gc0 + j) < (unsigned)IN_N) f[j] = xr[gc0 + j];
                }
                p.x = pk(f[0], f[1]); p.y = pk(f[2], f[3]);
                p.z = pk(f[4], f[5]); p.w = pk(f[6], f[7]);
            }
            *(v4u*)(&buf[row * XS + 8 * u]) = p;
        }
    }
}

// pipelined stage, part 1: issue global loads, hold raw f32 (no cvt, no wait)
__device__ __forceinline__ void issue_loads(
    const float* __restrict__ x, int tid, int R0, int X0, v2f L[4][4])
{
    #pragma unroll
    for (int s = 0; s < 4; ++s) {
        int i = s * 256 + tid;
        if (i < XROWS * 10) {
            int row = i / 10, u = i - 10 * row;
            const float* xr = x + (size_t)(R0 - 1 + row) * IN_N + (X0 - 2 + 8 * u);
            L[s][0] = *(const v2f*)(xr + 0);
            L[s][1] = *(const v2f*)(xr + 2);
            L[s][2] = *(const v2f*)(xr + 4);
            L[s][3] = *(const v2f*)(xr + 6);
        }
    }
}

// pipelined stage, part 2: cvt held data + ds_write (after compute)
__device__ __forceinline__ void write_held(
    unsigned short* __restrict__ buf, int tid, v2f L[4][4])
{
    #pragma unroll
    for (int s = 0; s < 4; ++s) {
        int i = s * 256 + tid;
        if (i < XROWS * 10) {
            int row = i / 10, u = i - 10 * row;
            v4u p;
            p.x = pk(L[s][0].x, L[s][0].y);
            p.y = pk(L[s][1].x, L[s][1].y);
            p.z = pk(L[s][2].x, L[s][2].y);
            p.w = pk(L[s][3].x, L[s][3].y);
            *(v4u*)(&buf[row * XS + 8 * u]) = p;
        }
    }
}

// 4 stacked 64x64 tiles per block; double-buffered LDS; B in LDS.
// Per tile: issue next loads -> compute (pure DS+MFMA) -> store -> write next.
__global__ __launch_bounds__(256, 3) void conv2d_mfma8(
    const float* __restrict__ x, const unsigned short* __restrict__ Bg,
    const float* __restrict__ bias, float* __restrict__ out)
{
    __shared__ unsigned short xt[2][XROWS * XS] __attribute__((aligned(16)));
    __shared__ unsigned short Bl[KS * 64 * 8]  __attribute__((aligned(16)));

    const int tid = threadIdx.x;
    const int bx = blockIdx.x, by = blockIdx.y;
    const int X0  = bx * TILE;
    const int RT0 = by * TILES;
    const bool colInt = (bx >= 1) & (bx <= NBX - 2);

    // copy B fragments into LDS (960 16B units)
    {
        const v8s* Bgs = (const v8s*)Bg;
        v8s* Bls = (v8s*)Bl;
        #pragma unroll
        for (int s = 0; s < 4; ++s) {
            int i = s * 256 + tid;
            if (i < KS * 64) Bls[i] = Bgs[i];
        }
    }

    // prologue: stage tile RT0 into xt[0]
    stage_direct(x, xt[0], tid, RT0 * TILE, X0,
                 colInt & (RT0 >= 1) & (RT0 <= NRT - 2));
    __syncthreads();

    const int lane = tid & 63;
    const int wv   = tid >> 6;
    const int m    = lane & 15;
    const int quad = lane >> 4;
    const float bv = bias[0];

    v2f L[4][4];

    #pragma unroll
    for (int t = 0; t < TILES; ++t) {
        const int RT = RT0 + t;
        const int R0 = RT * TILE;
        const unsigned short* cur = xt[t & 1];
        unsigned short* nxt = xt[(t + 1) & 1];
        const bool hasNext = (t < TILES - 1);
        const bool nFast = hasNext & colInt & ((RT + 1) <= NRT - 2);

        // 1) issue next tile's loads (held raw; latency hides under compute)
        if (nFast) issue_loads(x, tid, (RT + 1) * TILE, X0, L);
        __builtin_amdgcn_sched_barrier(0);

        // 2) compute current tile: pure LDS + MFMA (no VMEM dependencies)
        v4f acc[4];
        #pragma unroll
        for (int c = 0; c < 4; ++c) acc[c] = (v4f){0.f, 0.f, 0.f, 0.f};

        const unsigned short* arow = &cur[(wv * 16 + m) * XS + quad * 8];
        #pragma unroll
        for (int ky = 0; ky < KS; ++ky) {
            v8h bf = *(const v8h*)(&Bl[(ky * 64 + lane) * 8]);
            v8h a0 = *(const v8h*)(arow + 0);
            v8h a1 = *(const v8h*)(arow + 16);
            v8h a2 = *(const v8h*)(arow + 32);
            v8h a3 = *(const v8h*)(arow + 48);
            acc[0] = __builtin_amdgcn_mfma_f32_16x16x32_f16(a0, bf, acc[0], 0, 0, 0);
            acc[1] = __builtin_amdgcn_mfma_f32_16x16x32_f16(a1, bf, acc[1], 0, 0, 0);
            acc[2] = __builtin_amdgcn_mfma_f32_16x16x32_f16(a2, bf, acc[2], 0, 0, 0);
            acc[3] = __builtin_amdgcn_mfma_f32_16x16x32_f16(a3, bf, acc[3], 0, 0, 0);
            arow += XS;
        }

        // 3) store current tile
        const int orow0 = R0 + wv * 16 + quad * 4;
        const int ocol0 = X0 + m;
        if ((bx < NBX - 1) & (RT < NRT - 1)) {
            float* o0 = &out[(size_t)orow0 * OW + ocol0];
            #pragma unroll
            for (int c = 0; c < 4; ++c) {
                #pragma unroll
                for (int r = 0; r < 4; ++r)
                    o0[(size_t)r * OW + c * 16] = acc[c][r] + bv;
            }
        } else {
            #pragma unroll
            for (int c = 0; c < 4; ++c) {
                int oc = ocol0 + c * 16;
                if (oc < OW) {
                    #pragma unroll
                    for (int r = 0; r < 4; ++r) {
                        int orow = orow0 + r;
                        if (orow < OW)
                            out[(size_t)orow * OW + oc] = acc[c][r] + bv;
                    }
                }
            }
        }
        __builtin_amdgcn_sched_barrier(0);

        // 4) cvt + ds_write next tile into the other buffer
        if (hasNext) {
            if (nFast) write_held(nxt, tid, L);
            else       stage_direct(x, nxt, tid, (RT + 1) * TILE, X0, false);
        }
        __syncthreads();
    }
}

extern "C" void kernel_launch(void* const* d_in, const int* in_sizes, int n_in,
                              void* d_out, int out_size, void* d_ws, size_t ws_size,
                              hipStream_t stream) {
    const float* x    = (const float*)d_in[0];
    const float* w    = (const float*)d_in[1];
    const float* bias = (const float*)d_in[2];
    float* out        = (float*)d_out;
    unsigned short* Bg = (unsigned short*)d_ws;     // 15 KiB of scratch

    build_B<<<dim3(KS), dim3(64), 0, stream>>>(w, Bg);
    dim3 grid(NBX, NBY);
    conv2d_mfma8<<<grid, dim3(256), 0, stream>>>(x, Bg, bias, out);
}

// Round 7
// 151.491 us; speedup vs baseline: 1.0053x; 1.0053x over previous
//
#include <hip/hip_runtime.h>

#define IN_N   4096
#define OW     4084          // (4096 + 2*1 - 15) + 1
#define KS     15
#define TILE   64            // 64x64 output tile
#define XROWS  78            // TILE + 14 halo rows
#define XS     88            // f16 LDS row stride in halfwords
#define TILES  8             // stacked row-tiles per block
#define NBX    64
#define NBY    8
#define NRT    64            // total row tiles
#define RAWCH  98            // DMA chunks of 64 f32 (78*80=6240 used, pad to 6272)

typedef __attribute__((ext_vector_type(8))) short     v8s;   // raw 16B
typedef __attribute__((ext_vector_type(8))) _Float16  v8h;   // f16 A/B frag (4 VGPR)
typedef __attribute__((ext_vector_type(4))) float     v4f;   // C/D frag
typedef __attribute__((ext_vector_type(2))) float     v2f;
typedef __attribute__((ext_vector_type(2))) unsigned  v2u;
typedef __attribute__((ext_vector_type(4))) unsigned  v4u;

// ---- pre-kernel: build the 15 banded-B MFMA fragments once into d_ws ----
// B_ky[k][n] = w[ky, k-1-n]; A k-window starts at even global col X0-2.
// lane e holds B[k = (e>>4)*8 + j][n = e&15], j = 0..7  (16 B per lane)
__global__ void build_B(const float* __restrict__ w, unsigned short* __restrict__ Bg) {
    int ky = blockIdx.x;         // 15
    int e  = threadIdx.x;        // 64
    int n = e & 15, quad = e >> 4;
    unsigned short vals[8];
    #pragma unroll
    for (int j = 0; j < 8; ++j) {
        int d = quad * 8 + j - 1 - n;                 // shifted band
        _Float16 h = (_Float16)0.0f;
        if (d >= 0 && d < KS) h = (_Float16)w[ky * KS + d];
        union { _Float16 hh; unsigned short u; } cv; cv.hh = h;
        vals[j] = cv.u;
    }
    *(v8s*)(&Bg[(ky * 64 + e) * 8]) = *(const v8s*)vals;
}

__device__ __forceinline__ unsigned pk(float a, float b) {
    return __builtin_bit_cast(unsigned, __builtin_amdgcn_cvt_pkrtz(a, b));
}

// async DMA: one dword per lane, LDS dest = wave-uniform base + lane*4
__device__ __forceinline__ void gl_lds4(const float* g, float* l) {
    __builtin_amdgcn_global_load_lds(
        (const __attribute__((address_space(1))) void*)g,
        (__attribute__((address_space(3))) void*)l, 4, 0, 0);
}

// direct stage (prologue + edge tiles): global->VGPR->cvt->f16 LDS
__device__ __forceinline__ void stage_direct(
    const float* __restrict__ x, unsigned short* __restrict__ buf,
    int tid, int R0, int X0, bool fast)
{
    #pragma unroll
    for (int s = 0; s < 4; ++s) {
        int i = s * 256 + tid;
        if (i < XROWS * 10) {
            int row = i / 10, u = i - 10 * row;
            int gr  = R0 - 1 + row;
            int gc0 = X0 - 2 + 8 * u;
            v4u p;
            if (fast) {
                const float* xr = x + (size_t)gr * IN_N + gc0;
                v2f f0 = *(const v2f*)(xr + 0);
                v2f f1 = *(const v2f*)(xr + 2);
                v2f f2 = *(const v2f*)(xr + 4);
                v2f f3 = *(const v2f*)(xr + 6);
                p.x = pk(f0.x, f0.y); p.y = pk(f1.x, f1.y);
                p.z = pk(f2.x, f2.y); p.w = pk(f3.x, f3.y);
            } else {
                float f[8];
                #pragma unroll
                for (int j = 0; j < 8; ++j) f[j] = 0.0f;
                if ((unsigned)gr < (unsigned)IN_N) {
                    const float* xr = x + (size_t)gr * IN_N;
                    #pragma unroll
                    for (int j = 0; j < 8; ++j)
                        if ((unsigned)(gc0 + j) < (unsigned)IN_N) f[j] = xr[gc0 + j];
                }
                p.x = pk(f[0], f[1]); p.y = pk(f[2], f[3]);
                p.z = pk(f[4], f[5]); p.w = pk(f[6], f[7]);
            }
            *(v4u*)(&buf[row * XS + 8 * u]) = p;
        }
    }
}

// issue the whole next-tile raw f32 region as fire-and-forget DMA into LDS.
// raw layout: linear, f32 index f = row*80 + col, row 0..77, col 0..79
// (global: (R0n-1+row, X0-2+col)); chunk c covers f = c*64 .. c*64+63.
__device__ __forceinline__ void dma_raw(
    const float* __restrict__ x, float* __restrict__ raw,
    int wv, int lane, int R0n, int X0)
{
    const float* xb = x + (size_t)(R0n - 1) * IN_N + (X0 - 2);
    #pragma unroll
    for (int s = 0; s < 25; ++s) {
        int c = s * 4 + wv;                  // wave-uniform chunk id
        if (c < RAWCH) {
            int f = c * 64 + lane;
            f = (f < XROWS * 80) ? f : (XROWS * 80 - 1);   // clamp pad lanes
            int row = f / 80;
            int col = f - row * 80;
            gl_lds4(xb + (size_t)row * IN_N + col, raw + c * 64);
        }
    }
}

// LDS->LDS cvt pass: raw f32 -> f16 tile (1560 16B-units)
__device__ __forceinline__ void cvt_raw(
    const float* __restrict__ raw, unsigned short* __restrict__ xt, int tid)
{
    #pragma unroll
    for (int s = 0; s < 7; ++s) {
        int e = s * 256 + tid;
        if (e < XROWS * 20) {
            int row = e / 20, u = e - 20 * row;
            v4f d = *(const v4f*)(raw + e * 4);         // 16B-aligned
            v2u p;
            p.x = pk(d.x, d.y);
            p.y = pk(d.z, d.w);
            *(v2u*)(&xt[row * XS + 4 * u]) = p;         // 8B-aligned b64
        }
    }
}

// 8 stacked tiles per block; DMA prefetch of raw f32 overlaps compute by
// construction; single raw + single f16 buffer; B in LDS (compute is VMEM-free).
__global__ __launch_bounds__(256, 2) void conv2d_mfma9(
    const float* __restrict__ x, const unsigned short* __restrict__ Bg,
    const float* __restrict__ bias, float* __restrict__ out)
{
    __shared__ float          rawf[RAWCH * 64]      __attribute__((aligned(16)));
    __shared__ unsigned short xtile[XROWS * XS]     __attribute__((aligned(16)));
    __shared__ unsigned short Bl[KS * 64 * 8]       __attribute__((aligned(16)));

    const int tid = threadIdx.x;
    const int bx = blockIdx.x, by = blockIdx.y;
    const int X0  = bx * TILE;
    const int RT0 = by * TILES;
    const bool colInt = (bx >= 1) & (bx <= NBX - 2);

    // B fragments -> LDS (960 16B units)
    {
        const v8s* Bgs = (const v8s*)Bg;
        v8s* Bls = (v8s*)Bl;
        #pragma unroll
        for (int s = 0; s < 4; ++s) {
            int i = s * 256 + tid;
            if (i < KS * 64) Bls[i] = Bgs[i];
        }
    }

    // prologue: stage first f16 tile directly
    stage_direct(x, xtile, tid, RT0 * TILE, X0,
                 colInt & (RT0 >= 1) & (RT0 <= NRT - 2));
    __syncthreads();

    const int lane = tid & 63;
    const int wv   = tid >> 6;
    const int m    = lane & 15;
    const int quad = lane >> 4;
    const float bv = bias[0];

    #pragma unroll 1
    for (int t = 0; t < TILES; ++t) {
        const int RT = RT0 + t;
        const int R0 = RT * TILE;
        const bool hasNext = (t < TILES - 1);
        const bool nFast = hasNext & colInt & ((RT + 1) <= NRT - 2);

        // 1) fire-and-forget DMA of next tile's raw f32 into LDS
        if (nFast) dma_raw(x, rawf, wv, lane, (RT + 1) * TILE, X0);

        // 2) compute current tile: pure LDS + MFMA (no VMEM -> no vmcnt waits)
        v4f acc[4];
        #pragma unroll
        for (int c = 0; c < 4; ++c) acc[c] = (v4f){0.f, 0.f, 0.f, 0.f};

        const unsigned short* arow = &xtile[(wv * 16 + m) * XS + quad * 8];
        #pragma unroll
        for (int ky = 0; ky < KS; ++ky) {
            v8h bf = *(const v8h*)(&Bl[(ky * 64 + lane) * 8]);
            v8h a0 = *(const v8h*)(arow + 0);
            v8h a1 = *(const v8h*)(arow + 16);
            v8h a2 = *(const v8h*)(arow + 32);
            v8h a3 = *(const v8h*)(arow + 48);
            acc[0] = __builtin_amdgcn_mfma_f32_16x16x32_f16(a0, bf, acc[0], 0, 0, 0);
            acc[1] = __builtin_amdgcn_mfma_f32_16x16x32_f16(a1, bf, acc[1], 0, 0, 0);
            acc[2] = __builtin_amdgcn_mfma_f32_16x16x32_f16(a2, bf, acc[2], 0, 0, 0);
            acc[3] = __builtin_amdgcn_mfma_f32_16x16x32_f16(a3, bf, acc[3], 0, 0, 0);
            arow += XS;
        }

        // 3) DMA complete (had the whole compute phase); join the block
        asm volatile("s_waitcnt vmcnt(0)" ::: "memory");
        __syncthreads();

        // 4) store current tile (issues now, drains under next compute)
        const int orow0 = R0 + wv * 16 + quad * 4;
        const int ocol0 = X0 + m;
        if ((bx < NBX - 1) & (RT < NRT - 1)) {
            float* o0 = &out[(size_t)orow0 * OW + ocol0];
            #pragma unroll
            for (int c = 0; c < 4; ++c) {
                #pragma unroll
                for (int r = 0; r < 4; ++r)
                    o0[(size_t)r * OW + c * 16] = acc[c][r] + bv;
            }
        } else {
            #pragma unroll
            for (int c = 0; c < 4; ++c) {
                int oc = ocol0 + c * 16;
                if (oc < OW) {
                    #pragma unroll
                    for (int r = 0; r < 4; ++r) {
                        int orow = orow0 + r;
                        if (orow < OW)
                            out[(size_t)orow * OW + oc] = acc[c][r] + bv;
                    }
                }
            }
        }

        // 5) produce next f16 tile (LDS->LDS cvt, or bounded direct for edges)
        if (hasNext) {
            if (nFast) cvt_raw(rawf, xtile, tid);
            else       stage_direct(x, xtile, tid, (RT + 1) * TILE, X0, false);
        }
        __syncthreads();
    }
}

extern "C" void kernel_launch(void* const* d_in, const int* in_sizes, int n_in,
                              void* d_out, int out_size, void* d_ws, size_t ws_size,
                              hipStream_t stream) {
    const float* x    = (const float*)d_in[0];
    const float* w    = (const float*)d_in[1];
    const float* bias = (const float*)d_in[2];
    float* out        = (float*)d_out;
    unsigned short* Bg = (unsigned short*)d_ws;     // 15 KiB of scratch

    build_B<<<dim3(KS), dim3(64), 0, stream>>>(w, Bg);
    dim3 grid(NBX, NBY);
    conv2d_mfma9<<<grid, dim3(256), 0, stream>>>(x, Bg, bias, out);
}

// Round 8
// 138.663 us; speedup vs baseline: 1.0983x; 1.0925x over previous
//
#include <hip/hip_runtime.h>

#define IN_N   4096
#define OW     4084          // (4096 + 2*1 - 15) + 1
#define KS     15
#define TILE   64            // 64x64 output tile per block (4 waves x 16 rows)
#define XROWS  78            // TILE + KS - 1
#define XS     88            // LDS row stride in halfwords (176 B: 16B-mult)
#define NBX    64
#define NBY    64

typedef __attribute__((ext_vector_type(8))) short     v8s;   // raw 16B
typedef __attribute__((ext_vector_type(8))) _Float16  v8h;   // f16 A/B frag (4 VGPR)
typedef __attribute__((ext_vector_type(4))) float     v4f;   // C/D frag
typedef __attribute__((ext_vector_type(2))) float     v2f;
typedef __attribute__((ext_vector_type(2))) unsigned  v2u;

// ---- pre-kernel: build the 15 banded-B MFMA fragments once into d_ws ----
// B_ky[k][n] = w[ky, k-1-n] (band k ∈ [n+1, n+15]); A k-window starts at EVEN
// global col X0-2 -> aligned float2 staging.
// lane e holds B[k = (e>>4)*8 + j][n = e&15], j = 0..7  (16 B per lane)
__global__ void build_B(const float* __restrict__ w, unsigned short* __restrict__ Bg) {
    int ky = blockIdx.x;         // 15
    int e  = threadIdx.x;        // 64
    int n = e & 15, quad = e >> 4;
    unsigned short vals[8];
    #pragma unroll
    for (int j = 0; j < 8; ++j) {
        int d = quad * 8 + j - 1 - n;                 // shifted band
        _Float16 h = (_Float16)0.0f;
        if (d >= 0 && d < KS) h = (_Float16)w[ky * KS + d];   // RTNE f32->f16
        union { _Float16 hh; unsigned short u; } cv; cv.hh = h;
        vals[j] = cv.u;
    }
    *(v8s*)(&Bg[(ky * 64 + e) * 8]) = *(const v8s*)vals;
}

__device__ __forceinline__ unsigned pk(float a, float b) {
    return __builtin_bit_cast(unsigned, __builtin_amdgcn_cvt_pkrtz(a, b));
}

// R1 structure; interior stage split into issue-all / write-all for deep MLP.
__global__ __launch_bounds__(256, 6) void conv2d_mfma10(
    const float* __restrict__ x, const unsigned short* __restrict__ Bg,
    const float* __restrict__ bias, float* __restrict__ out)
{
    __shared__ unsigned short xtile[XROWS * XS] __attribute__((aligned(16)));

    const int tid = threadIdx.x;
    const int bx = blockIdx.x, by = blockIdx.y;
    const int X0 = bx * TILE;
    const int Y0 = by * TILE;
    const bool interior = (bx > 0) & (bx < NBX - 1) & (by > 0) & (by < NBY - 1);

    // ---- stage input tile fp32 -> f16 ----
    // LDS (row, col) = global (Y0-1+row, X0-2+col), col in [0,80)
    // 240 threads as 12 rows x 20 four-col units; 7 row-sweeps cover 78 rows.
    if (tid < 240) {
        const int tcol = tid % 20;
        const int trow = tid / 20;                    // 0..11
        const int c0 = 4 * tcol;                      // halfword col, 8B-aligned
        unsigned short* dst = &xtile[trow * XS + c0];
        if (interior) {
            // phase 1: issue ALL loads (14 dwordx2 in flight -> 1 latency exposure)
            v2f Ld[7][2];
            const float* xr = x + (size_t)(Y0 - 1 + trow) * IN_N + (X0 - 2 + c0);
            #pragma unroll
            for (int i = 0; i < 7; ++i) {
                if (i < 6 || trow < 6) {              // rows 72..77 on last sweep
                    Ld[i][0] = *(const v2f*)xr;
                    Ld[i][1] = *(const v2f*)(xr + 2);
                }
                xr += 12 * (size_t)IN_N;
            }
            // phase 2: cvt + ds_write (consumes loads in issue order)
            #pragma unroll
            for (int i = 0; i < 7; ++i) {
                if (i < 6 || trow < 6) {
                    v2u p;
                    p.x = pk(Ld[i][0].x, Ld[i][0].y);
                    p.y = pk(Ld[i][1].x, Ld[i][1].y);
                    *(v2u*)dst = p;                   // ds_write_b64
                }
                dst += 12 * XS;
            }
        } else {
            const int gc0 = X0 - 2 + c0;
            #pragma unroll
            for (int i = 0; i < 7; ++i) {
                int row = trow + 12 * i;
                if (row < XROWS) {
                    int gr = Y0 - 1 + row;
                    float f0 = 0.f, f1 = 0.f, f2 = 0.f, f3 = 0.f;
                    if ((unsigned)gr < (unsigned)IN_N) {
                        const float* xr = x + (size_t)gr * IN_N;
                        if ((unsigned)(gc0 + 0) < (unsigned)IN_N) f0 = xr[gc0 + 0];
                        if ((unsigned)(gc0 + 1) < (unsigned)IN_N) f1 = xr[gc0 + 1];
                        if ((unsigned)(gc0 + 2) < (unsigned)IN_N) f2 = xr[gc0 + 2];
                        if ((unsigned)(gc0 + 3) < (unsigned)IN_N) f3 = xr[gc0 + 3];
                    }
                    v2u p;
                    p.x = pk(f0, f1);
                    p.y = pk(f2, f3);
                    *(v2u*)(&xtile[row * XS + c0]) = p;
                }
            }
        }
    }
    __syncthreads();

    // ---- MFMA main loop (rolling B prefetch, as in the 51.4 µs best) ----
    const int lane = tid & 63;
    const int wv   = tid >> 6;
    const int m    = lane & 15;
    const int quad = lane >> 4;

    v4f acc[4];
    #pragma unroll
    for (int t = 0; t < 4; ++t) acc[t] = (v4f){0.f, 0.f, 0.f, 0.f};

    const v8h* Bgv = (const v8h*)Bg;
    v8h bcur = Bgv[lane];                             // ky = 0 (L2-resident)
    const unsigned short* arow = &xtile[(wv * 16 + m) * XS + quad * 8];

    #pragma unroll
    for (int ky = 0; ky < KS; ++ky) {
        v8h bnext = (ky < KS - 1) ? Bgv[(ky + 1) * 64 + lane] : bcur;
        v8h a0 = *(const v8h*)(arow + 0);             // ds_read_b128 x4
        v8h a1 = *(const v8h*)(arow + 16);
        v8h a2 = *(const v8h*)(arow + 32);
        v8h a3 = *(const v8h*)(arow + 48);
        acc[0] = __builtin_amdgcn_mfma_f32_16x16x32_f16(a0, bcur, acc[0], 0, 0, 0);
        acc[1] = __builtin_amdgcn_mfma_f32_16x16x32_f16(a1, bcur, acc[1], 0, 0, 0);
        acc[2] = __builtin_amdgcn_mfma_f32_16x16x32_f16(a2, bcur, acc[2], 0, 0, 0);
        acc[3] = __builtin_amdgcn_mfma_f32_16x16x32_f16(a3, bcur, acc[3], 0, 0, 0);
        arow += XS;
        bcur = bnext;
    }

    // ---- epilogue: D[m,n] -> out; row = quad*4 + r, col = m (+16t) ----
    const float bv = bias[0];
    const int orow0 = Y0 + wv * 16 + quad * 4;
    const int ocol0 = X0 + m;
    if (interior | ((bx < NBX - 1) & (by < NBY - 1))) {
        float* o0 = &out[(size_t)orow0 * OW + ocol0];
        #pragma unroll
        for (int t = 0; t < 4; ++t) {
            #pragma unroll
            for (int r = 0; r < 4; ++r)
                o0[(size_t)r * OW + t * 16] = acc[t][r] + bv;
        }
    } else {
        #pragma unroll
        for (int t = 0; t < 4; ++t) {
            int oc = ocol0 + t * 16;
            if (oc < OW) {
                #pragma unroll
                for (int r = 0; r < 4; ++r) {
                    int orow = orow0 + r;
                    if (orow < OW)
                        out[(size_t)orow * OW + oc] = acc[t][r] + bv;
                }
            }
        }
    }
}

extern "C" void kernel_launch(void* const* d_in, const int* in_sizes, int n_in,
                              void* d_out, int out_size, void* d_ws, size_t ws_size,
                              hipStream_t stream) {
    const float* x    = (const float*)d_in[0];
    const float* w    = (const float*)d_in[1];
    const float* bias = (const float*)d_in[2];
    float* out        = (float*)d_out;
    unsigned short* Bg = (unsigned short*)d_ws;     // 15 KiB of scratch

    build_B<<<dim3(KS), dim3(64), 0, stream>>>(w, Bg);
    dim3 grid(NBX, NBY);
    conv2d_mfma10<<<grid, dim3(256), 0, stream>>>(x, Bg, bias, out);
}